// Round 9
// baseline (184.919 us; speedup 1.0000x reference)
//
#include <hip/hip_runtime.h>
#include <hip/hip_fp16.h>
#include <cmath>

// Problem constants: (N,C,H,W) = (16,3,512,512), fp32
#define PLANE (512*512)          // 262144
#define NPLANES 48               // N*C
#define NEL (48*PLANE)           // 12582912

struct Taps { float k[9]; };
struct CMat { float w[3][3]; };   // C-axis 9-tap blur collapsed to 3x3 matrix

// ws layout (fp16, ROW-CONTIGUOUS, plane-strided):
//   ushort index(z, h, w) = (h*96 + z)*512 + w        z = plane 0..95
//   wsS[0 .. 2*NEL) : HW-blurred log, planes 0..47 = image E, 48..95 = G
// I is NOT staged: K2 re-reads the fp32 inputs (L3-resident).

#define FOLD(r) ((r) < 0 ? (-1 - (r)) : ((r) > 511 ? (1023 - (r)) : (r)))

__device__ __forceinline__ uint swap16(uint x) { return (x >> 16) | (x << 16); }
// pack(x) for odd x: lo = hi(pack(x-1)), hi = lo(pack(x+1))
__device__ __forceinline__ uint align16(uint hiSrc, uint loSrc) {
    return (loSrc >> 16) | (hiSrc << 16);
}

// ---------------------------------------------------------------------------
// Kernel 1: fused log + W-blur + H-blur (NO I staging).
// ONE wave per (16-row strip x 256-col HALF-row): 4 cols/lane -> 6144 waves
// = 24/CU (6/SIMD), 2x the memory-level parallelism of all prior rounds at
// ~constant traffic (vertical amp still 1.5; W-halo = predicated float4 +
// 4 logs on ONLY the 2 boundary lanes). Bijective XCD swizzle makes
// halo-sharing adjacent rowgroups XCD-contiguous (halo reads hit local L2).
// Datapath bit-identical to the R7/R8-verified adjacent-pair fp16 chains.
// grid 6144 x block 64. Block hw==0 zeroes the loss accumulator.
// ---------------------------------------------------------------------------
__global__ __launch_bounds__(64, 6)
void k_blur_hw(const float* __restrict__ inE, const float* __restrict__ inG,
               ushort* __restrict__ wsS, float* __restrict__ out, Taps tp)
{
    const int  l  = threadIdx.x;              // 0..63 -> cols w0+4l..w0+4l+3
    const uint hw = blockIdx.x;
    if (hw == 0 && l == 0) *out = 0.f;        // stream-ordered before k_cn_loss
    // XCD swizzle: hw%8 = XCD; give each XCD 768 consecutive virtual blocks
    const uint v  = (hw & 7u) * 768u + (hw >> 3);
    const int rg = (int)(v & 31u);            // rowgroup 0..31 (adjacent on same XCD)
    const int pc = (int)(v >> 5);             // (plane, half) 0..191
    const int z  = pc >> 1;                   // plane 0..95
    const int w0 = (pc & 1) * 256;            // column half
    const int r0 = rg * 16;
    const float* __restrict__ src = (z < NPLANES) ? (inE + z * PLANE)
                                                  : (inG + (z - NPLANES) * PLANE);
    const int col = w0 + 4 * l;

    const bool haloL   = (l == 0  && w0 != 0);   // needs cols w0-4..w0-1
    const bool haloR   = (l == 63 && w0 == 0);   // needs cols 256..259
    const bool do_halo = haloL || haloR;
    const int  hcol    = (l == 0) ? (w0 - 4) : (w0 + 256);

    __half2 kh[9];
#pragma unroll
    for (int t = 0; t < 9; ++t) kh[t] = __float2half2_rn(tp.k[t]);

    uint ring[9][2];                          // W-blurred rows, adjacent pairs

    // depth-4 circular prefetch (own), depth-2 (halo, L2-hot neighbor data)
    float4 pA[4], pH[2];
#pragma unroll
    for (int s = 0; s < 4; ++s)
        pA[s] = *(const float4*)(src + FOLD(r0 - 4 + s) * 512 + col);
    pH[0] = pH[1] = make_float4(1.f, 1.f, 1.f, 1.f);
#pragma unroll
    for (int s = 0; s < 2; ++s)
        if (do_halo) pH[s] = *(const float4*)(src + FOLD(r0 - 4 + s) * 512 + hcol);

#pragma unroll
    for (int j = 0; j < 24; ++j) {            // input row r0-4+j (full unroll)
        const float4 a = pA[j % 4];
        const float4 hb = pH[j % 2];
        if (j + 4 < 24)                       // refill own slot (4-iter slack)
            pA[j % 4] = *(const float4*)(src + FOLD(r0 + j) * 512 + col);
        if (j + 2 < 24 && do_halo)            // refill halo slot (2-iter slack)
            pH[j % 2] = *(const float4*)(src + FOLD(r0 - 2 + j) * 512 + hcol);

        // fp32 log -> adjacent-pair fp16 packs (own 4 cols)
        __half2 h01 = __floats2half2_rn(__logf(a.x + 1e-6f), __logf(a.y + 1e-6f));
        __half2 h23 = __floats2half2_rn(__logf(a.z + 1e-6f), __logf(a.w + 1e-6f));
        const uint P0 = *(uint*)&h01, P2 = *(uint*)&h23;

        // halo packs (only 2 lanes execute the logs)
        uint H0 = 0, H2 = 0;
        if (do_halo) {
            __half2 g01 = __floats2half2_rn(__logf(hb.x + 1e-6f), __logf(hb.y + 1e-6f));
            __half2 g23 = __floats2half2_rn(__logf(hb.z + 1e-6f), __logf(hb.w + 1e-6f));
            H0 = *(uint*)&g01; H2 = *(uint*)&g23;
        }

        // window packs: pk[x] = (w[col-4+x], w[col-3+x]), x = 0..10
        uint U0 = (uint)__shfl_up((int)P0, 1);    // (col-4, col-3)
        uint U2 = (uint)__shfl_up((int)P2, 1);    // (col-2, col-1)
        uint D0 = (uint)__shfl_down((int)P0, 1);  // (col+4, col+5)
        uint D2 = (uint)__shfl_down((int)P2, 1);  // (col+6, col+7)
        if (l == 0) {
            if (w0 == 0) { U0 = swap16(P2); U2 = swap16(P0); }   // reflect 3,2 / 1,0
            else         { U0 = H0;         U2 = H2;         }   // cols 252..255
        }
        if (l == 63) {
            if (w0 != 0) { D0 = swap16(P2); D2 = swap16(P0); }   // reflect 511,510 / 509,508
            else         { D0 = H0;         D2 = H2;         }   // cols 256..259
        }
        uint pk[11];
        pk[0] = U0; pk[2] = U2; pk[4] = P0; pk[6] = P2; pk[8] = D0; pk[10] = D2;
#pragma unroll
        for (int x = 0; x < 5; ++x) pk[2 * x + 1] = align16(pk[2 * x + 2], pk[2 * x]);

        // W-blur: uint q = pair (out[col+2q], out[col+2q+1])
#pragma unroll
        for (int q = 0; q < 2; ++q) {
            __half2 acc = __hmul2(kh[0], *(__half2*)&pk[2 * q]);
#pragma unroll
            for (int t = 1; t < 9; ++t)
                acc = __hfma2(kh[t], *(__half2*)&pk[2 * q + t], acc);
            ring[j % 9][q] = *(uint*)&acc;
        }

        // H-blur + store once 9 rows live (output row r0+j-8)
        if (j >= 8) {
            __half2 s0, s1;
            {
                const int sl = (j - 8) % 9;
                s0 = __hmul2(kh[0], *(__half2*)&ring[sl][0]);
                s1 = __hmul2(kh[0], *(__half2*)&ring[sl][1]);
            }
#pragma unroll
            for (int t = 1; t < 9; ++t) {
                const int sl = (j - 8 + t) % 9;       // compile-time (full unroll)
                s0 = __hfma2(kh[t], *(__half2*)&ring[sl][0], s0);
                s1 = __hfma2(kh[t], *(__half2*)&ring[sl][1], s1);
            }
            const int ro = r0 + j - 8;
            ushort* dpS = wsS + ((ro * 96) + z) * 512 + col;   // 512B/wave contiguous
            *(uint2*)dpS = make_uint2(*(uint*)&s0, *(uint*)&s1);
        }
    }
}

// ---------------------------------------------------------------------------
// Kernel 2: C-blur + N-blur + loss. TWO adjacent (h,w) points per thread;
// S from warm fp16 ws (row-major: plane q at +q*512), I+eps from the
// ORIGINAL fp32 inputs (one coalesced float2 per plane, L3-resident).
// grid (512), block (256). (R8-verified version, unchanged)
// ---------------------------------------------------------------------------
__global__ __launch_bounds__(256)
void k_cn_loss(const ushort* __restrict__ wsS,
               const float* __restrict__ inE, const float* __restrict__ inG,
               float* __restrict__ out, Taps tp, CMat cm)
{
    const int tid = threadIdx.x;
    const int P   = blockIdx.x * 256 + tid;      // pair index
    const int hw0 = P * 2;                       // first point (even col)
    const int h   = hw0 >> 9;
    const int w0  = hw0 & 511;
    const ushort* sbase = wsS + (size_t)(h * 96) * 512 + w0;
    // E plane q: uint at +q*512; G plane q: +(48+q)*512
    const float* __restrict__ ibE = inE + (size_t)h * 512 + w0;
    const float* __restrict__ ibG = inG + (size_t)h * 512 + w0;
    // plane p at + p*PLANE (float2 covers the pair (w0, w0+1))

    __half2 k2[9], cw[3][3];
#pragma unroll
    for (int t = 0; t < 9; ++t) k2[t] = __float2half2_rn(tp.k[t]);
#pragma unroll
    for (int i = 0; i < 3; ++i)
#pragma unroll
        for (int j = 0; j < 3; ++j) cw[i][j] = __float2half2_rn(cm.w[i][j]);

    __half2 re[9][3];   // ring of C-blurred smoothed-log(E), slot = m % 9
    __half2 rg[9][3];

#define LOADRAW(m, uE, uG)                                                     \
    uE[0] = *(const uint*)(sbase + ((m) * 3 + 0) * 512);                       \
    uE[1] = *(const uint*)(sbase + ((m) * 3 + 1) * 512);                       \
    uE[2] = *(const uint*)(sbase + ((m) * 3 + 2) * 512);                       \
    uG[0] = *(const uint*)(sbase + (48 + (m) * 3 + 0) * 512);                  \
    uG[1] = *(const uint*)(sbase + (48 + (m) * 3 + 1) * 512);                  \
    uG[2] = *(const uint*)(sbase + (48 + (m) * 3 + 2) * 512);

#define CBLUR(u, dst)                                                          \
    {                                                                          \
        __half2 v0 = *(__half2*)&u[0];                                         \
        __half2 v1 = *(__half2*)&u[1];                                         \
        __half2 v2 = *(__half2*)&u[2];                                         \
        dst[0] = __hfma2(cw[0][0], v0, __hfma2(cw[0][1], v1, __hmul2(cw[0][2], v2))); \
        dst[1] = __hfma2(cw[1][0], v0, __hfma2(cw[1][1], v1, __hmul2(cw[1][2], v2))); \
        dst[2] = __hfma2(cw[2][0], v0, __hfma2(cw[2][1], v1, __hmul2(cw[2][2], v2))); \
    }

#pragma unroll
    for (int m = 0; m < 4; ++m) {
        uint uE[3], uG[3];
        LOADRAW(m, uE, uG);
        CBLUR(uE, re[m]); CBLUR(uG, rg[m]);
    }
    uint nuE[3], nuG[3];
    LOADRAW(4, nuE, nuG);
    float2 fe[3], fg[3];                         // fp32 I pairs
#pragma unroll
    for (int c = 0; c < 3; ++c) {
        fe[c] = *(const float2*)(ibE + (size_t)c * PLANE);
        fg[c] = *(const float2*)(ibG + (size_t)c * PLANE);
    }

    float acc = 0.f;
#pragma unroll
    for (int n = 0; n < 16; ++n) {
        float2 nfe[3], nfg[3];
        if (n + 1 < 16) {
#pragma unroll
            for (int c = 0; c < 3; ++c) {
                nfe[c] = *(const float2*)(ibE + (size_t)((n + 1) * 3 + c) * PLANE);
                nfg[c] = *(const float2*)(ibG + (size_t)((n + 1) * 3 + c) * PLANE);
            }
        }
        const int mnew = n + 4;
        if (mnew < 16) {
            CBLUR(nuE, re[mnew % 9]); CBLUR(nuG, rg[mnew % 9]);
            if (mnew + 1 < 16) { LOADRAW(mnew + 1, nuE, nuG); }
        }
#pragma unroll
        for (int c = 0; c < 3; ++c) {
            __half2 se2 = __float2half2_rn(0.f), sg2 = se2;
#pragma unroll
            for (int t = 0; t < 9; ++t) {
                int m = n - 4 + t;
                m = (m < 0) ? (-1 - m) : ((m > 15) ? (31 - m) : m);  // compile-time
                se2 = __hfma2(k2[t], re[m % 9][c], se2);
                sg2 = __hfma2(k2[t], rg[m % 9][c], sg2);
            }
            const float2 sef = __half22float2(se2);
            const float2 sgf = __half22float2(sg2);

            // point 0
            {
                float ee = __expf(-sef.x), eg = __expf(-sgf.x);
                float Re = (fe[c].x + 1e-6f) * ee;
                float Rg = (fg[c].x + 1e-6f) * eg;
                float Le = __builtin_amdgcn_rcpf(ee);
                float Lg = __builtin_amdgcn_rcpf(eg);
                float dr = Re - Rg, dl = Le - Lg;
                acc += dr * dr + dl * dl;
            }
            // point 1
            {
                float ee = __expf(-sef.y), eg = __expf(-sgf.y);
                float Re = (fe[c].y + 1e-6f) * ee;
                float Rg = (fg[c].y + 1e-6f) * eg;
                float Le = __builtin_amdgcn_rcpf(ee);
                float Lg = __builtin_amdgcn_rcpf(eg);
                float dr = Re - Rg, dl = Le - Lg;
                acc += dr * dr + dl * dl;
            }
        }
        if (n + 1 < 16) {
#pragma unroll
            for (int c = 0; c < 3; ++c) { fe[c] = nfe[c]; fg[c] = nfg[c]; }
        }
    }
#undef LOADRAW
#undef CBLUR

    __shared__ float red[256];
    red[tid] = acc;
    __syncthreads();
#pragma unroll
    for (int s = 128; s > 0; s >>= 1) {
        if (tid < s) red[tid] += red[tid + s];
        __syncthreads();
    }
    if (tid == 0) atomicAdd(out, red[0] * (1.0f / (float)NEL));
}

extern "C" void kernel_launch(void* const* d_in, const int* in_sizes, int n_in,
                              void* d_out, int out_size, void* d_ws, size_t ws_size,
                              hipStream_t stream) {
    const float* Ie = (const float*)d_in[0];
    const float* Ig = (const float*)d_in[1];

    // Gaussian taps: sigma=1, radius=int(4*1+0.5)=4, double-precision normalize
    Taps tp;
    {
        double kk[9], s = 0.0;
        for (int i = 0; i < 9; ++i) { double x = (double)(i - 4); kk[i] = exp(-0.5 * x * x); s += kk[i]; }
        for (int i = 0; i < 9; ++i) tp.k[i] = (float)(kk[i] / s);
    }

    // C-axis (size 3) 9-tap symmetric blur collapsed to a 3x3 matrix
    CMat cm;
    {
        for (int c = 0; c < 3; ++c) {
            cm.w[c][0] = cm.w[c][1] = cm.w[c][2] = 0.f;
            for (int t = 0; t < 9; ++t) {
                int m = c - 4 + t;
                int mm = ((m % 6) + 6) % 6;          // symmetric reflect, period 6
                if (mm > 2) mm = 5 - mm;
                cm.w[c][mm] += tp.k[t];
            }
        }
    }

    ushort* wsS = (ushort*)d_ws;                 // fp16 blurred logs, 50.3 MB

    k_blur_hw<<<6144, 64, 0, stream>>>(Ie, Ig, wsS, (float*)d_out, tp);
    k_cn_loss<<<512, 256, 0, stream>>>(wsS, Ie, Ig, (float*)d_out, tp, cm);
}

// Round 10
// 169.052 us; speedup vs baseline: 1.0939x; 1.0939x over previous
//
#include <hip/hip_runtime.h>
#include <hip/hip_fp16.h>
#include <cmath>

// Problem constants: (N,C,H,W) = (16,3,512,512), fp32
#define PLANE (512*512)          // 262144
#define NPLANES 48               // N*C
#define NEL (48*PLANE)           // 12582912

struct Taps { float k[9]; };
struct CMat { float w[3][3]; };   // C-axis 9-tap blur collapsed to 3x3 matrix

// ws layout (fp16, ROW-CONTIGUOUS, plane-strided):
//   ushort index(z, h, w) = (h*96 + z)*512 + w        z = plane 0..95
//   wsS[0 .. 2*NEL) : HW-blurred log, planes 0..47 = image E, 48..95 = G
// I is NOT staged: K2 re-reads the fp32 inputs (L3-resident).

#define FOLD(r) ((r) < 0 ? (-1 - (r)) : ((r) > 511 ? (1023 - (r)) : (r)))

__device__ __forceinline__ uint swap16(uint x) { return (x >> 16) | (x << 16); }
// pack(x) for odd x: lo = hi(pack(x-1)), hi = lo(pack(x+1))
__device__ __forceinline__ uint align16(uint hiSrc, uint loSrc) {
    return (loSrc >> 16) | (hiSrc << 16);
}

// ---------------------------------------------------------------------------
// Kernel 1: fused log + W-blur + H-blur (NO I staging).
// ONE wave per (16-row strip x 256-col HALF-row): 4 cols/lane -> 6144 waves
// = 24/CU. R9 retry WITHOUT spills: R9's forced launch_bounds(64,6) made the
// compiler spill ~20 regs/lane (WRITE 49152->81408 KB, exact match) which
// poisoned the occupancy experiment. Here: pA depth 3 (was 4), ring[9][2],
// launch_bounds(64,5) (cap 102, lands naturally ~75-85 -> 5-6 waves/SIMD).
// R5 evidence: 24 w/CU lifts effective BW 2.44 -> ~3.0 TB/s.
// Datapath + halo/edge logic bit-identical to R9-verified (absmax 0.0).
// grid 6144 x block 64. Block hw==0 zeroes the loss accumulator.
// ---------------------------------------------------------------------------
__global__ __launch_bounds__(64, 5)
void k_blur_hw(const float* __restrict__ inE, const float* __restrict__ inG,
               ushort* __restrict__ wsS, float* __restrict__ out, Taps tp)
{
    const int  l  = threadIdx.x;              // 0..63 -> cols w0+4l..w0+4l+3
    const uint hw = blockIdx.x;
    if (hw == 0 && l == 0) *out = 0.f;        // stream-ordered before k_cn_loss
    // XCD swizzle: hw%8 = XCD; give each XCD 768 consecutive virtual blocks
    const uint v  = (hw & 7u) * 768u + (hw >> 3);
    const int rg = (int)(v & 31u);            // rowgroup 0..31 (adjacent on same XCD)
    const int pc = (int)(v >> 5);             // (plane, half) 0..191
    const int z  = pc >> 1;                   // plane 0..95
    const int w0 = (pc & 1) * 256;            // column half
    const int r0 = rg * 16;
    const float* __restrict__ src = (z < NPLANES) ? (inE + z * PLANE)
                                                  : (inG + (z - NPLANES) * PLANE);
    const int col = w0 + 4 * l;

    const bool haloL   = (l == 0  && w0 != 0);   // needs cols w0-4..w0-1
    const bool haloR   = (l == 63 && w0 == 0);   // needs cols 256..259
    const bool do_halo = haloL || haloR;
    const int  hcol    = (l == 0) ? (w0 - 4) : (w0 + 256);

    __half2 kh[9];
#pragma unroll
    for (int t = 0; t < 9; ++t) kh[t] = __float2half2_rn(tp.k[t]);

    uint ring[9][2];                          // W-blurred rows, adjacent pairs

    // depth-3 circular prefetch (own), depth-2 (halo, L2-hot neighbor data)
    float4 pA[3], pH[2];
#pragma unroll
    for (int s = 0; s < 3; ++s)
        pA[s] = *(const float4*)(src + FOLD(r0 - 4 + s) * 512 + col);
    pH[0] = pH[1] = make_float4(1.f, 1.f, 1.f, 1.f);
#pragma unroll
    for (int s = 0; s < 2; ++s)
        if (do_halo) pH[s] = *(const float4*)(src + FOLD(r0 - 4 + s) * 512 + hcol);

#pragma unroll
    for (int j = 0; j < 24; ++j) {            // input row r0-4+j (full unroll)
        const float4 a  = pA[j % 3];
        const float4 hb = pH[j % 2];
        if (j + 3 < 24)                       // refill own slot (3-iter slack)
            pA[j % 3] = *(const float4*)(src + FOLD(r0 - 1 + j) * 512 + col);
        if (j + 2 < 24 && do_halo)            // refill halo slot (2-iter slack)
            pH[j % 2] = *(const float4*)(src + FOLD(r0 - 2 + j) * 512 + hcol);

        // fp32 log -> adjacent-pair fp16 packs (own 4 cols)
        __half2 h01 = __floats2half2_rn(__logf(a.x + 1e-6f), __logf(a.y + 1e-6f));
        __half2 h23 = __floats2half2_rn(__logf(a.z + 1e-6f), __logf(a.w + 1e-6f));
        const uint P0 = *(uint*)&h01, P2 = *(uint*)&h23;

        // halo packs (only 2 lanes execute the logs)
        uint H0 = 0, H2 = 0;
        if (do_halo) {
            __half2 g01 = __floats2half2_rn(__logf(hb.x + 1e-6f), __logf(hb.y + 1e-6f));
            __half2 g23 = __floats2half2_rn(__logf(hb.z + 1e-6f), __logf(hb.w + 1e-6f));
            H0 = *(uint*)&g01; H2 = *(uint*)&g23;
        }

        // window packs: pk[x] = (w[col-4+x], w[col-3+x]), x = 0..10
        uint U0 = (uint)__shfl_up((int)P0, 1);    // (col-4, col-3)
        uint U2 = (uint)__shfl_up((int)P2, 1);    // (col-2, col-1)
        uint D0 = (uint)__shfl_down((int)P0, 1);  // (col+4, col+5)
        uint D2 = (uint)__shfl_down((int)P2, 1);  // (col+6, col+7)
        if (l == 0) {
            if (w0 == 0) { U0 = swap16(P2); U2 = swap16(P0); }   // reflect 3,2 / 1,0
            else         { U0 = H0;         U2 = H2;         }   // cols 252..255
        }
        if (l == 63) {
            if (w0 != 0) { D0 = swap16(P2); D2 = swap16(P0); }   // reflect 511,510 / 509,508
            else         { D0 = H0;         D2 = H2;         }   // cols 256..259
        }
        uint pk[11];
        pk[0] = U0; pk[2] = U2; pk[4] = P0; pk[6] = P2; pk[8] = D0; pk[10] = D2;
#pragma unroll
        for (int x = 0; x < 5; ++x) pk[2 * x + 1] = align16(pk[2 * x + 2], pk[2 * x]);

        // W-blur: uint q = pair (out[col+2q], out[col+2q+1])
#pragma unroll
        for (int q = 0; q < 2; ++q) {
            __half2 acc = __hmul2(kh[0], *(__half2*)&pk[2 * q]);
#pragma unroll
            for (int t = 1; t < 9; ++t)
                acc = __hfma2(kh[t], *(__half2*)&pk[2 * q + t], acc);
            ring[j % 9][q] = *(uint*)&acc;
        }

        // H-blur + store once 9 rows live (output row r0+j-8)
        if (j >= 8) {
            __half2 s0, s1;
            {
                const int sl = (j - 8) % 9;
                s0 = __hmul2(kh[0], *(__half2*)&ring[sl][0]);
                s1 = __hmul2(kh[0], *(__half2*)&ring[sl][1]);
            }
#pragma unroll
            for (int t = 1; t < 9; ++t) {
                const int sl = (j - 8 + t) % 9;       // compile-time (full unroll)
                s0 = __hfma2(kh[t], *(__half2*)&ring[sl][0], s0);
                s1 = __hfma2(kh[t], *(__half2*)&ring[sl][1], s1);
            }
            const int ro = r0 + j - 8;
            ushort* dpS = wsS + ((ro * 96) + z) * 512 + col;   // 512B/wave contiguous
            *(uint2*)dpS = make_uint2(*(uint*)&s0, *(uint*)&s1);
        }
    }
}

// ---------------------------------------------------------------------------
// Kernel 2: C-blur + N-blur + loss. TWO adjacent (h,w) points per thread;
// S from warm fp16 ws (row-major: plane q at +q*512), I+eps from the
// ORIGINAL fp32 inputs (one coalesced float2 per plane, L3-resident).
// grid (512), block (256). (R8-verified version, unchanged)
// ---------------------------------------------------------------------------
__global__ __launch_bounds__(256)
void k_cn_loss(const ushort* __restrict__ wsS,
               const float* __restrict__ inE, const float* __restrict__ inG,
               float* __restrict__ out, Taps tp, CMat cm)
{
    const int tid = threadIdx.x;
    const int P   = blockIdx.x * 256 + tid;      // pair index
    const int hw0 = P * 2;                       // first point (even col)
    const int h   = hw0 >> 9;
    const int w0  = hw0 & 511;
    const ushort* sbase = wsS + (size_t)(h * 96) * 512 + w0;
    // E plane q: uint at +q*512; G plane q: +(48+q)*512
    const float* __restrict__ ibE = inE + (size_t)h * 512 + w0;
    const float* __restrict__ ibG = inG + (size_t)h * 512 + w0;
    // plane p at + p*PLANE (float2 covers the pair (w0, w0+1))

    __half2 k2[9], cw[3][3];
#pragma unroll
    for (int t = 0; t < 9; ++t) k2[t] = __float2half2_rn(tp.k[t]);
#pragma unroll
    for (int i = 0; i < 3; ++i)
#pragma unroll
        for (int j = 0; j < 3; ++j) cw[i][j] = __float2half2_rn(cm.w[i][j]);

    __half2 re[9][3];   // ring of C-blurred smoothed-log(E), slot = m % 9
    __half2 rg[9][3];

#define LOADRAW(m, uE, uG)                                                     \
    uE[0] = *(const uint*)(sbase + ((m) * 3 + 0) * 512);                       \
    uE[1] = *(const uint*)(sbase + ((m) * 3 + 1) * 512);                       \
    uE[2] = *(const uint*)(sbase + ((m) * 3 + 2) * 512);                       \
    uG[0] = *(const uint*)(sbase + (48 + (m) * 3 + 0) * 512);                  \
    uG[1] = *(const uint*)(sbase + (48 + (m) * 3 + 1) * 512);                  \
    uG[2] = *(const uint*)(sbase + (48 + (m) * 3 + 2) * 512);

#define CBLUR(u, dst)                                                          \
    {                                                                          \
        __half2 v0 = *(__half2*)&u[0];                                         \
        __half2 v1 = *(__half2*)&u[1];                                         \
        __half2 v2 = *(__half2*)&u[2];                                         \
        dst[0] = __hfma2(cw[0][0], v0, __hfma2(cw[0][1], v1, __hmul2(cw[0][2], v2))); \
        dst[1] = __hfma2(cw[1][0], v0, __hfma2(cw[1][1], v1, __hmul2(cw[1][2], v2))); \
        dst[2] = __hfma2(cw[2][0], v0, __hfma2(cw[2][1], v1, __hmul2(cw[2][2], v2))); \
    }

#pragma unroll
    for (int m = 0; m < 4; ++m) {
        uint uE[3], uG[3];
        LOADRAW(m, uE, uG);
        CBLUR(uE, re[m]); CBLUR(uG, rg[m]);
    }
    uint nuE[3], nuG[3];
    LOADRAW(4, nuE, nuG);
    float2 fe[3], fg[3];                         // fp32 I pairs
#pragma unroll
    for (int c = 0; c < 3; ++c) {
        fe[c] = *(const float2*)(ibE + (size_t)c * PLANE);
        fg[c] = *(const float2*)(ibG + (size_t)c * PLANE);
    }

    float acc = 0.f;
#pragma unroll
    for (int n = 0; n < 16; ++n) {
        float2 nfe[3], nfg[3];
        if (n + 1 < 16) {
#pragma unroll
            for (int c = 0; c < 3; ++c) {
                nfe[c] = *(const float2*)(ibE + (size_t)((n + 1) * 3 + c) * PLANE);
                nfg[c] = *(const float2*)(ibG + (size_t)((n + 1) * 3 + c) * PLANE);
            }
        }
        const int mnew = n + 4;
        if (mnew < 16) {
            CBLUR(nuE, re[mnew % 9]); CBLUR(nuG, rg[mnew % 9]);
            if (mnew + 1 < 16) { LOADRAW(mnew + 1, nuE, nuG); }
        }
#pragma unroll
        for (int c = 0; c < 3; ++c) {
            __half2 se2 = __float2half2_rn(0.f), sg2 = se2;
#pragma unroll
            for (int t = 0; t < 9; ++t) {
                int m = n - 4 + t;
                m = (m < 0) ? (-1 - m) : ((m > 15) ? (31 - m) : m);  // compile-time
                se2 = __hfma2(k2[t], re[m % 9][c], se2);
                sg2 = __hfma2(k2[t], rg[m % 9][c], sg2);
            }
            const float2 sef = __half22float2(se2);
            const float2 sgf = __half22float2(sg2);

            // point 0
            {
                float ee = __expf(-sef.x), eg = __expf(-sgf.x);
                float Re = (fe[c].x + 1e-6f) * ee;
                float Rg = (fg[c].x + 1e-6f) * eg;
                float Le = __builtin_amdgcn_rcpf(ee);
                float Lg = __builtin_amdgcn_rcpf(eg);
                float dr = Re - Rg, dl = Le - Lg;
                acc += dr * dr + dl * dl;
            }
            // point 1
            {
                float ee = __expf(-sef.y), eg = __expf(-sgf.y);
                float Re = (fe[c].y + 1e-6f) * ee;
                float Rg = (fg[c].y + 1e-6f) * eg;
                float Le = __builtin_amdgcn_rcpf(ee);
                float Lg = __builtin_amdgcn_rcpf(eg);
                float dr = Re - Rg, dl = Le - Lg;
                acc += dr * dr + dl * dl;
            }
        }
        if (n + 1 < 16) {
#pragma unroll
            for (int c = 0; c < 3; ++c) { fe[c] = nfe[c]; fg[c] = nfg[c]; }
        }
    }
#undef LOADRAW
#undef CBLUR

    __shared__ float red[256];
    red[tid] = acc;
    __syncthreads();
#pragma unroll
    for (int s = 128; s > 0; s >>= 1) {
        if (tid < s) red[tid] += red[tid + s];
        __syncthreads();
    }
    if (tid == 0) atomicAdd(out, red[0] * (1.0f / (float)NEL));
}

extern "C" void kernel_launch(void* const* d_in, const int* in_sizes, int n_in,
                              void* d_out, int out_size, void* d_ws, size_t ws_size,
                              hipStream_t stream) {
    const float* Ie = (const float*)d_in[0];
    const float* Ig = (const float*)d_in[1];

    // Gaussian taps: sigma=1, radius=int(4*1+0.5)=4, double-precision normalize
    Taps tp;
    {
        double kk[9], s = 0.0;
        for (int i = 0; i < 9; ++i) { double x = (double)(i - 4); kk[i] = exp(-0.5 * x * x); s += kk[i]; }
        for (int i = 0; i < 9; ++i) tp.k[i] = (float)(kk[i] / s);
    }

    // C-axis (size 3) 9-tap symmetric blur collapsed to a 3x3 matrix
    CMat cm;
    {
        for (int c = 0; c < 3; ++c) {
            cm.w[c][0] = cm.w[c][1] = cm.w[c][2] = 0.f;
            for (int t = 0; t < 9; ++t) {
                int m = c - 4 + t;
                int mm = ((m % 6) + 6) % 6;          // symmetric reflect, period 6
                if (mm > 2) mm = 5 - mm;
                cm.w[c][mm] += tp.k[t];
            }
        }
    }

    ushort* wsS = (ushort*)d_ws;                 // fp16 blurred logs, 50.3 MB

    k_blur_hw<<<6144, 64, 0, stream>>>(Ie, Ig, wsS, (float*)d_out, tp);
    k_cn_loss<<<512, 256, 0, stream>>>(wsS, Ie, Ig, (float*)d_out, tp, cm);
}

// Round 11
// 157.943 us; speedup vs baseline: 1.1708x; 1.0703x over previous
//
#include <hip/hip_runtime.h>
#include <hip/hip_fp16.h>
#include <cmath>

// Problem constants: (N,C,H,W) = (16,3,512,512), fp32
#define PLANE (512*512)          // 262144
#define NPLANES 48               // N*C
#define NEL (48*PLANE)           // 12582912

struct Taps { float k[9]; };
struct CMat { float w[3][3]; };   // C-axis 9-tap blur collapsed to 3x3 matrix

// ws layout (fp16, ROW-CONTIGUOUS, plane-strided):
//   ushort index(z, h, w) = (h*96 + z)*512 + w        z = plane 0..95
//   wsS[0 .. 2*NEL) : HW-blurred log, planes 0..47 = image E, 48..95 = G
// I is NOT staged: K2 re-reads the fp32 inputs (L3-resident).

#define FOLD(r) ((r) < 0 ? (-1 - (r)) : ((r) > 511 ? (1023 - (r)) : (r)))

__device__ __forceinline__ uint swap16(uint x) { return (x >> 16) | (x << 16); }
// pack(x) for odd x: lo = hi(pack(x-1)), hi = lo(pack(x+1))
__device__ __forceinline__ uint align16(uint hiSrc, uint loSrc) {
    return (loSrc >> 16) | (hiSrc << 16);
}

// ---------------------------------------------------------------------------
// Kernel 1: fused log + W-blur + H-blur (NO I staging).  R8-EXACT REVERT
// (best measured config: 50.1-52.3 us; R9/R10 occupancy variants regressed).
// ONE wave per (16-row strip x FULL 512-col row) of one plane: 8 cols/lane,
// no barriers. Depth-6 indexed-circular global prefetch. Adjacent-pair fp16
// packing. 1024B-contiguous wave stores (row-major ws layout).
// grid (32, 96), block 64 -> 3072 waves = 12/CU, amp 24/16 = 1.5.
// Block (0,0) zeroes the loss accumulator (replaces memset dispatch).
// ---------------------------------------------------------------------------
__global__ __launch_bounds__(64, 3)
void k_blur_hw(const float* __restrict__ inE, const float* __restrict__ inG,
               ushort* __restrict__ wsS, float* __restrict__ out, Taps tp)
{
    const int l  = threadIdx.x;               // 0..63 -> cols 8l..8l+7
    const int r0 = blockIdx.x * 16;           // 32 rowgroups
    const int z  = blockIdx.y;                // plane 0..95
    if (blockIdx.x == 0 && blockIdx.y == 0 && l == 0) *out = 0.f;
    const float* __restrict__ src = (z < NPLANES) ? (inE + z * PLANE)
                                                  : (inG + (z - NPLANES) * PLANE);
    const int col = 8 * l;

    __half2 kh[9];
#pragma unroll
    for (int t = 0; t < 9; ++t) kh[t] = __float2half2_rn(tp.k[t]);

    uint ring[12][4];                         // W-blurred rows, adjacent pairs

    // depth-6 indexed circular prefetch over rows r0-4+j
    float4 pA[6], pB[6];
#pragma unroll
    for (int s = 0; s < 6; ++s) {
        const int row = FOLD(r0 - 4 + s);
        pA[s] = *(const float4*)(src + row * 512 + col);
        pB[s] = *(const float4*)(src + row * 512 + col + 4);
    }

    for (int jb = 0; jb < 24; jb += 12) {
#pragma unroll
        for (int u = 0; u < 12; ++u) {
            const int j   = jb + u;           // input row r0-4+j
            const int sl6 = u % 6;            // compile-time (12 % 6 == 0)

            const float4 a = pA[sl6], b = pB[sl6];
            if (j + 6 < 24) {                 // refill slot for row j+6
                const int row = FOLD(r0 + 2 + j);
                pA[sl6] = *(const float4*)(src + row * 512 + col);
                pB[sl6] = *(const float4*)(src + row * 512 + col + 4);
            }

            // fp32 log -> adjacent-pair fp16 packs
            const float e0 = __logf(a.x + 1e-6f), e1 = __logf(a.y + 1e-6f);
            const float e2 = __logf(a.z + 1e-6f), e3 = __logf(a.w + 1e-6f);
            const float e4 = __logf(b.x + 1e-6f), e5 = __logf(b.y + 1e-6f);
            const float e6 = __logf(b.z + 1e-6f), e7 = __logf(b.w + 1e-6f);
            __half2 h01 = __floats2half2_rn(e0, e1);
            __half2 h23 = __floats2half2_rn(e2, e3);
            __half2 h45 = __floats2half2_rn(e4, e5);
            __half2 h67 = __floats2half2_rn(e6, e7);
            const uint P0 = *(uint*)&h01, P2 = *(uint*)&h23;
            const uint P4 = *(uint*)&h45, P6 = *(uint*)&h67;

            // pk[x+4] = (w[col+x], w[col+x+1]), x = -4..10
            uint U4 = (uint)__shfl_up((int)P4, 1);    // (w[col-4], w[col-3])
            uint U6 = (uint)__shfl_up((int)P6, 1);    // (w[col-2], w[col-1])
            uint D0 = (uint)__shfl_down((int)P0, 1);  // (w[col+8], w[col+9])
            uint D2 = (uint)__shfl_down((int)P2, 1);  // (w[col+10], w[col+11])
            if (l == 0)  { U4 = swap16(P2); U6 = swap16(P0); }  // reflect 3,2 / 1,0
            if (l == 63) { D0 = swap16(P6); D2 = swap16(P4); }  // reflect 511,510 / 509,508
            uint pk[15];
            pk[0] = U4; pk[2] = U6; pk[4] = P0; pk[6] = P2;
            pk[8] = P4; pk[10] = P6; pk[12] = D0; pk[14] = D2;
#pragma unroll
            for (int x = 0; x < 7; ++x) pk[2 * x + 1] = align16(pk[2 * x + 2], pk[2 * x]);

            // W-blur: uint q = pair (out[col+2q], out[col+2q+1])
#pragma unroll
            for (int q = 0; q < 4; ++q) {
                __half2 acc = __hmul2(kh[0], *(__half2*)&pk[2 * q]);
#pragma unroll
                for (int t = 1; t < 9; ++t)
                    acc = __hfma2(kh[t], *(__half2*)&pk[2 * q + t], acc);
                ring[u][q] = *(uint*)&acc;
            }

            // H-blur + store once 9 rows live (output row r0+j-8)
            if (j >= 8) {
                __half2 s0, s1, s2, s3;
                {
                    const int sl = (u + 4) % 12;          // slot of row j-8
                    s0 = __hmul2(kh[0], *(__half2*)&ring[sl][0]);
                    s1 = __hmul2(kh[0], *(__half2*)&ring[sl][1]);
                    s2 = __hmul2(kh[0], *(__half2*)&ring[sl][2]);
                    s3 = __hmul2(kh[0], *(__half2*)&ring[sl][3]);
                }
#pragma unroll
                for (int t = 1; t < 9; ++t) {
                    const int sl = (u + 4 + t) % 12;      // compile-time
                    s0 = __hfma2(kh[t], *(__half2*)&ring[sl][0], s0);
                    s1 = __hfma2(kh[t], *(__half2*)&ring[sl][1], s1);
                    s2 = __hfma2(kh[t], *(__half2*)&ring[sl][2], s2);
                    s3 = __hfma2(kh[t], *(__half2*)&ring[sl][3], s3);
                }
                const int ro = r0 + j - 8;
                ushort* dpS = wsS + ((ro * 96) + z) * 512 + col;   // contiguous wave store
                *(uint4*)dpS = make_uint4(*(uint*)&s0, *(uint*)&s1,
                                          *(uint*)&s2, *(uint*)&s3);
            }
        }
    }
}

// ---------------------------------------------------------------------------
// Kernel 2: C-blur + N-blur + loss. TWO adjacent (h,w) points per thread;
// S from warm fp16 ws, I+eps from the ORIGINAL fp32 inputs. DEEPENED
// SOFTWARE PIPELINES vs R8 (only change; math/datapath bit-identical):
//   - I loads: 3 rotating buffers f0/f1/f2, issued 3 n-iterations ahead
//     (was 1) -- covers L3 latency (~500+ cyc) at only 2 waves/SIMD.
//   - S loads: parity pair sA/sB, CBLUR'd 2 iterations after issue (was 1).
// All buffer indices compile-time (n-loop fully unrolled, named buffers).
// grid (512), block (256).
// ---------------------------------------------------------------------------
__global__ __launch_bounds__(256)
void k_cn_loss(const ushort* __restrict__ wsS,
               const float* __restrict__ inE, const float* __restrict__ inG,
               float* __restrict__ out, Taps tp, CMat cm)
{
    const int tid = threadIdx.x;
    const int P   = blockIdx.x * 256 + tid;      // pair index
    const int hw0 = P * 2;                       // first point (even col)
    const int h   = hw0 >> 9;
    const int w0  = hw0 & 511;
    const ushort* sbase = wsS + (size_t)(h * 96) * 512 + w0;
    // E plane q: uint at +q*512; G plane q: +(48+q)*512
    const float* __restrict__ ibE = inE + (size_t)h * 512 + w0;
    const float* __restrict__ ibG = inG + (size_t)h * 512 + w0;
    // plane p at + p*PLANE (float2 covers the pair (w0, w0+1))

    __half2 k2[9], cw[3][3];
#pragma unroll
    for (int t = 0; t < 9; ++t) k2[t] = __float2half2_rn(tp.k[t]);
#pragma unroll
    for (int i = 0; i < 3; ++i)
#pragma unroll
        for (int j = 0; j < 3; ++j) cw[i][j] = __float2half2_rn(cm.w[i][j]);

    __half2 re[9][3];   // ring of C-blurred smoothed-log(E), slot = m % 9
    __half2 rg[9][3];

#define LOADRAW(m, uE, uG)                                                     \
    uE[0] = *(const uint*)(sbase + ((m) * 3 + 0) * 512);                       \
    uE[1] = *(const uint*)(sbase + ((m) * 3 + 1) * 512);                       \
    uE[2] = *(const uint*)(sbase + ((m) * 3 + 2) * 512);                       \
    uG[0] = *(const uint*)(sbase + (48 + (m) * 3 + 0) * 512);                  \
    uG[1] = *(const uint*)(sbase + (48 + (m) * 3 + 1) * 512);                  \
    uG[2] = *(const uint*)(sbase + (48 + (m) * 3 + 2) * 512);

#define LOADI(m, FE, FG)                                                       \
    FE[0] = *(const float2*)(ibE + (size_t)((m) * 3 + 0) * PLANE);             \
    FE[1] = *(const float2*)(ibE + (size_t)((m) * 3 + 1) * PLANE);             \
    FE[2] = *(const float2*)(ibE + (size_t)((m) * 3 + 2) * PLANE);             \
    FG[0] = *(const float2*)(ibG + (size_t)((m) * 3 + 0) * PLANE);             \
    FG[1] = *(const float2*)(ibG + (size_t)((m) * 3 + 1) * PLANE);             \
    FG[2] = *(const float2*)(ibG + (size_t)((m) * 3 + 2) * PLANE);

#define CBLUR(u, dst)                                                          \
    {                                                                          \
        __half2 v0 = *(__half2*)&u[0];                                         \
        __half2 v1 = *(__half2*)&u[1];                                         \
        __half2 v2 = *(__half2*)&u[2];                                         \
        dst[0] = __hfma2(cw[0][0], v0, __hfma2(cw[0][1], v1, __hmul2(cw[0][2], v2))); \
        dst[1] = __hfma2(cw[1][0], v0, __hfma2(cw[1][1], v1, __hmul2(cw[1][2], v2))); \
        dst[2] = __hfma2(cw[2][0], v0, __hfma2(cw[2][1], v1, __hmul2(cw[2][2], v2))); \
    }

    // prime ring with S rows 0..3
#pragma unroll
    for (int m = 0; m < 4; ++m) {
        uint uE[3], uG[3];
        LOADRAW(m, uE, uG);
        CBLUR(uE, re[m]); CBLUR(uG, rg[m]);
    }
    // S pipeline: sA = row 4, sB = row 5 (2-deep)
    uint sAE[3], sAG[3], sBE[3], sBG[3];
    LOADRAW(4, sAE, sAG);
    LOADRAW(5, sBE, sBG);
    // I pipeline: 3 rotating buffers (3-deep)
    float2 f0e[3], f0g[3], f1e[3], f1g[3], f2e[3], f2g[3];
    LOADI(0, f0e, f0g);
    LOADI(1, f1e, f1g);
    LOADI(2, f2e, f2g);

    float acc = 0.f;

    // Per-n step: CBLUR the ready S buffer (row n+4) into the ring, refill it
    // with row n+6; compute the loss for row n from the ready I buffer; refill
    // that I buffer with row n+3. All guards/indices compile-time.
#define STEP(n, SE, SG, FE, FG)                                                \
    {                                                                          \
        if ((n) + 4 < 16) {                                                    \
            CBLUR(SE, re[((n) + 4) % 9]); CBLUR(SG, rg[((n) + 4) % 9]);        \
            if ((n) + 6 < 16) { LOADRAW((n) + 6, SE, SG); }                    \
        }                                                                      \
        _Pragma("unroll")                                                      \
        for (int c = 0; c < 3; ++c) {                                          \
            __half2 se2 = __float2half2_rn(0.f), sg2 = se2;                    \
            _Pragma("unroll")                                                  \
            for (int t = 0; t < 9; ++t) {                                      \
                int m = (n) - 4 + t;                                           \
                m = (m < 0) ? (-1 - m) : ((m > 15) ? (31 - m) : m);            \
                se2 = __hfma2(k2[t], re[m % 9][c], se2);                       \
                sg2 = __hfma2(k2[t], rg[m % 9][c], sg2);                       \
            }                                                                  \
            const float2 sef = __half22float2(se2);                            \
            const float2 sgf = __half22float2(sg2);                            \
            {                                                                  \
                float ee = __expf(-sef.x), eg = __expf(-sgf.x);                \
                float Re = (FE[c].x + 1e-6f) * ee;                             \
                float Rg = (FG[c].x + 1e-6f) * eg;                             \
                float Le = __builtin_amdgcn_rcpf(ee);                          \
                float Lg = __builtin_amdgcn_rcpf(eg);                          \
                float dr = Re - Rg, dl = Le - Lg;                              \
                acc += dr * dr + dl * dl;                                      \
            }                                                                  \
            {                                                                  \
                float ee = __expf(-sef.y), eg = __expf(-sgf.y);                \
                float Re = (FE[c].y + 1e-6f) * ee;                             \
                float Rg = (FG[c].y + 1e-6f) * eg;                             \
                float Le = __builtin_amdgcn_rcpf(ee);                          \
                float Lg = __builtin_amdgcn_rcpf(eg);                          \
                float dr = Re - Rg, dl = Le - Lg;                              \
                acc += dr * dr + dl * dl;                                      \
            }                                                                  \
        }                                                                      \
        if ((n) + 3 < 16) { LOADI((n) + 3, FE, FG); }                          \
    }

    STEP(0,  sAE, sAG, f0e, f0g);
    STEP(1,  sBE, sBG, f1e, f1g);
    STEP(2,  sAE, sAG, f2e, f2g);
    STEP(3,  sBE, sBG, f0e, f0g);
    STEP(4,  sAE, sAG, f1e, f1g);
    STEP(5,  sBE, sBG, f2e, f2g);
    STEP(6,  sAE, sAG, f0e, f0g);
    STEP(7,  sBE, sBG, f1e, f1g);
    STEP(8,  sAE, sAG, f2e, f2g);
    STEP(9,  sBE, sBG, f0e, f0g);
    STEP(10, sAE, sAG, f1e, f1g);
    STEP(11, sBE, sBG, f2e, f2g);
    STEP(12, sAE, sAG, f0e, f0g);
    STEP(13, sBE, sBG, f1e, f1g);
    STEP(14, sAE, sAG, f2e, f2g);
    STEP(15, sBE, sBG, f0e, f0g);

#undef STEP
#undef LOADRAW
#undef LOADI
#undef CBLUR

    __shared__ float red[256];
    red[tid] = acc;
    __syncthreads();
#pragma unroll
    for (int s = 128; s > 0; s >>= 1) {
        if (tid < s) red[tid] += red[tid + s];
        __syncthreads();
    }
    if (tid == 0) atomicAdd(out, red[0] * (1.0f / (float)NEL));
}

extern "C" void kernel_launch(void* const* d_in, const int* in_sizes, int n_in,
                              void* d_out, int out_size, void* d_ws, size_t ws_size,
                              hipStream_t stream) {
    const float* Ie = (const float*)d_in[0];
    const float* Ig = (const float*)d_in[1];

    // Gaussian taps: sigma=1, radius=int(4*1+0.5)=4, double-precision normalize
    Taps tp;
    {
        double kk[9], s = 0.0;
        for (int i = 0; i < 9; ++i) { double x = (double)(i - 4); kk[i] = exp(-0.5 * x * x); s += kk[i]; }
        for (int i = 0; i < 9; ++i) tp.k[i] = (float)(kk[i] / s);
    }

    // C-axis (size 3) 9-tap symmetric blur collapsed to a 3x3 matrix
    CMat cm;
    {
        for (int c = 0; c < 3; ++c) {
            cm.w[c][0] = cm.w[c][1] = cm.w[c][2] = 0.f;
            for (int t = 0; t < 9; ++t) {
                int m = c - 4 + t;
                int mm = ((m % 6) + 6) % 6;          // symmetric reflect, period 6
                if (mm > 2) mm = 5 - mm;
                cm.w[c][mm] += tp.k[t];
            }
        }
    }

    ushort* wsS = (ushort*)d_ws;                 // fp16 blurred logs, 50.3 MB

    dim3 g1(32, 96);
    k_blur_hw<<<g1, 64, 0, stream>>>(Ie, Ig, wsS, (float*)d_out, tp);
    k_cn_loss<<<512, 256, 0, stream>>>(wsS, Ie, Ig, (float*)d_out, tp, cm);
}